// Round 1
// baseline (1034.940 us; speedup 1.0000x reference)
//
#include <hip/hip_runtime.h>
#include <hip/hip_bf16.h>
#include <math.h>

// ---------------------------------------------------------------------------
// GATEmbedding: CNN (4x conv3x3+relu+maxpool2) per slice -> fc -> GAT x2 -> heads
// All fp32. Outputs (flat, in order):
//   slices_hidden (8,128)  @0
//   image_feature_second (8,256) @1024
//   prediction (8,2) @3072
//   slices_out (8,2) @3088
//   batch_attention (8,19,19) @3104
// ---------------------------------------------------------------------------

#define NEG_INF_F (-9.0e15f)

// ---------------- adjacency (N=19, mid_nodes=3), row-normalized -------------
__global__ void adj_build_k(float* __restrict__ adj) {
  __shared__ float A[19][19];
  int t = threadIdx.x;
  if (t < 361) {
    int i = t / 19, j = t % 19;
    float v = 0.f;
    const int MIDN = 3, N = 19, MID = 10, WIDTH = 2;
    if (i < MIDN) {
      if (i == MIDN - 1) { if (j > MIDN - 1) v = 1.f; }
      else if (j == i + 1 || (j > MID - (i + 1) * WIDTH && j < MID + (i + 1) * WIDTH)) v = 1.f;
    } else {
      if (i == MIDN) { if (j == MIDN + 1) v = 1.f; }
      else if (i == N - 1) { if (j == N - 2) v = 1.f; }
      else if (j == i - 1 || j == i + 1) v = 1.f;
    }
    if (i == j) v += 1.f;
    A[i][j] = v;
  }
  __syncthreads();
  if (t < 361) {
    int i = t / 19;
    float rs = 0.f;
    for (int j = 0; j < 19; ++j) rs += A[i][j];
    float rinv = rs > 0.f ? 1.f / rs : 0.f;
    adj[t] = A[t / 19][t % 19] * rinv;
  }
}

// ---------------- conv1: 1->32 @128x128, fused relu+pool -> (img,32,64,64) --
__global__ __launch_bounds__(256) void conv1_pool_k(
    const float* __restrict__ in, const float* __restrict__ w,
    const float* __restrict__ bias, float* __restrict__ out) {
  const int img = blockIdx.z, oc = blockIdx.y;
  const int t = threadIdx.x;
  const int px = t & 63;
  const int py = (blockIdx.x << 2) + (t >> 6);
  const float* ip = in + (size_t)img * 16384;
  float wv[9];
#pragma unroll
  for (int k = 0; k < 9; ++k) wv[k] = w[oc * 9 + k];
  float mx = -1e30f;
#pragma unroll
  for (int dy = 0; dy < 2; ++dy)
#pragma unroll
    for (int dx = 0; dx < 2; ++dx) {
      int cy = 2 * py + dy, cx = 2 * px + dx;
      float a = 0.f;
#pragma unroll
      for (int ky = 0; ky < 3; ++ky)
#pragma unroll
        for (int kx = 0; kx < 3; ++kx) {
          int yy = cy - 1 + ky, xx = cx - 1 + kx;
          float v = (yy >= 0 && yy < 128 && xx >= 0 && xx < 128) ? ip[yy * 128 + xx] : 0.f;
          a = fmaf(v, wv[ky * 3 + kx], a);
        }
      mx = fmaxf(mx, a);
    }
  out[(((size_t)img * 32 + oc) << 12) + py * 64 + px] = fmaxf(mx + bias[oc], 0.f);
}

// ---------------- tiled conv+relu+pool template for conv2/3/4 ---------------
// block = 256 = 16 oc x 16 spatial threads; each thread: 2x2 pooled outputs.
// tile = 8x8 pooled (16x16 conv region, 18x18 input halo), ICB=8 input chans.
template <int CIN, int COUT, int HIN>
__global__ __launch_bounds__(256) void conv_pool_k(
    const float* __restrict__ in, const float* __restrict__ w,
    const float* __restrict__ bias, float* __restrict__ out) {
  constexpr int HP = HIN / 2;
  constexpr int ICB = 8;
  constexpr int TPD = HP / 8;
  const int img = blockIdx.z;
  const int ocb = blockIdx.y;
  const int ty = blockIdx.x / TPD;
  const int tx = blockIdx.x - ty * TPD;
  const int t = threadIdx.x;
  const int oct = t >> 4;
  const int sp = t & 15;
  const int thy = sp >> 2, thx = sp & 3;
  const int oc = ocb * 16 + oct;
  __shared__ float s_in[ICB][18][20];
  __shared__ float s_w[16][ICB][9];
  float acc[4][4];
#pragma unroll
  for (int a = 0; a < 4; ++a)
#pragma unroll
    for (int c = 0; c < 4; ++c) acc[a][c] = 0.f;
  const float* ip = in + (size_t)img * CIN * HIN * HIN;
  const int y0 = ty * 16 - 1, x0 = tx * 16 - 1;
  for (int ic0 = 0; ic0 < CIN; ic0 += ICB) {
    __syncthreads();
    for (int e = t; e < ICB * 324; e += 256) {
      int c = e / 324;
      int r = e - c * 324;
      int ry = r / 18, rx = r - ry * 18;
      int yy = y0 + ry, xx = x0 + rx;
      float v = 0.f;
      if (yy >= 0 && yy < HIN && xx >= 0 && xx < HIN)
        v = ip[(size_t)(ic0 + c) * (HIN * HIN) + yy * HIN + xx];
      s_in[c][ry][rx] = v;
    }
    for (int e = t; e < 16 * ICB * 9; e += 256) {
      int o = e / (ICB * 9);
      int rem = e - o * (ICB * 9);
      int c = rem / 9, kk = rem - c * 9;
      s_w[o][c][kk] = w[((size_t)(ocb * 16 + o) * CIN + ic0 + c) * 9 + kk];
    }
    __syncthreads();
#pragma unroll
    for (int c = 0; c < ICB; ++c) {
      float wv[9];
#pragma unroll
      for (int k = 0; k < 9; ++k) wv[k] = s_w[oct][c][k];
      float win[6][6];
#pragma unroll
      for (int r = 0; r < 6; ++r)
#pragma unroll
        for (int q = 0; q < 6; ++q) win[r][q] = s_in[c][thy * 4 + r][thx * 4 + q];
#pragma unroll
      for (int rr = 0; rr < 4; ++rr)
#pragma unroll
        for (int cc = 0; cc < 4; ++cc) {
          float a = acc[rr][cc];
#pragma unroll
          for (int ky = 0; ky < 3; ++ky)
#pragma unroll
            for (int kx = 0; kx < 3; ++kx)
              a = fmaf(win[rr + ky][cc + kx], wv[ky * 3 + kx], a);
          acc[rr][cc] = a;
        }
    }
  }
  const float bb = bias[oc];
  const int gpy0 = ty * 8 + thy * 2, gpx0 = tx * 8 + thx * 2;
#pragma unroll
  for (int pr = 0; pr < 2; ++pr)
#pragma unroll
    for (int pc = 0; pc < 2; ++pc) {
      float m = fmaxf(fmaxf(acc[2 * pr][2 * pc], acc[2 * pr][2 * pc + 1]),
                      fmaxf(acc[2 * pr + 1][2 * pc], acc[2 * pr + 1][2 * pc + 1]));
      out[((size_t)img * COUT + oc) * (HP * HP) + (gpy0 + pr) * HP + (gpx0 + pc)] =
          fmaxf(m + bb, 0.f);
    }
}

// ---------------- spatial mean + fc -> feats (128 imgs x 128) ---------------
__global__ __launch_bounds__(128) void meanfc_k(
    const float* __restrict__ c4, const float* __restrict__ fcw,
    const float* __restrict__ fcb, float* __restrict__ feats, int img0) {
  int img = blockIdx.x, t = threadIdx.x;
  __shared__ float sM[128];
  const float* p = c4 + (size_t)img * 8192 + t * 64;
  float s = 0.f;
  for (int i = 0; i < 64; ++i) s += p[i];
  sM[t] = s * (1.f / 64.f);
  __syncthreads();
  float a = fcb[t];
  for (int c = 0; c < 128; ++c) a = fmaf(sM[c], fcw[c * 128 + t], a);
  feats[(size_t)(img0 + img) * 128 + t] = a;
}

// ---------------- slices_hidden + slices_out --------------------------------
__global__ __launch_bounds__(128) void sh_k(
    const float* __restrict__ feats, const float* __restrict__ sfcw,
    const float* __restrict__ sfcb, float* __restrict__ out) {
  int b = blockIdx.x, t = threadIdx.x;
  __shared__ float sh[128];
  float s = 0.f;
  for (int c = 0; c < 16; ++c) s += feats[(size_t)(b * 16 + c) * 128 + t];
  s *= (1.f / 16.f);
  out[b * 128 + t] = s;
  sh[t] = s;
  __syncthreads();
  if (t < 2) {
    float a = sfcb[t];
    for (int e = 0; e < 128; ++e) a = fmaf(sh[e], sfcw[e * 2 + t], a);
    out[3088 + b * 2 + t] = a;
  }
}

// ---------------- Wh = slices @ att_W, plus f1/f2 projections ---------------
__global__ __launch_bounds__(64) void wh_k(
    const float* __restrict__ feats, const float* __restrict__ attW,
    const float* __restrict__ atta, float* __restrict__ Wh,
    float* __restrict__ f1, float* __restrict__ f2) {
  int bid = blockIdx.x;           // b*152 + k*19 + n
  int n = bid % 19;
  int k = (bid / 19) % 8;
  int b = bid / 152;
  int h = threadIdx.x;
  float acc = 0.f;
  if (n >= 3) {
    const float* s = feats + (size_t)(b * 16 + n - 3) * 128;
    const float* W = attW + (size_t)k * 8192 + h;
    for (int f = 0; f < 128; ++f) acc = fmaf(s[f], W[f * 64], acc);
  }
  Wh[(size_t)bid * 64 + h] = acc;
  float p1 = acc * atta[k * 128 + h];
  float p2 = acc * atta[k * 128 + 64 + h];
#pragma unroll
  for (int off = 32; off > 0; off >>= 1) {
    p1 += __shfl_down(p1, off);
    p2 += __shfl_down(p2, off);
  }
  if (h == 0) { f1[bid] = p1; f2[bid] = p2; }
}

// ---------------- masked softmax attention per (b,k) ------------------------
__global__ __launch_bounds__(64) void att_k(
    const float* __restrict__ f1, const float* __restrict__ f2,
    const float* __restrict__ adj, float* __restrict__ att) {
  int bk = blockIdx.x;  // b*8+k
  int i = threadIdx.x;
  __shared__ float sf2[19];
  if (i < 19) sf2[i] = f2[bk * 19 + i];
  __syncthreads();
  if (i >= 19) return;
  float fi = f1[bk * 19 + i];
  float v[19];
  float mx = -1e30f;
#pragma unroll
  for (int j = 0; j < 19; ++j) {
    float e = fi + sf2[j];
    e = e >= 0.f ? e : 0.2f * e;
    e = adj[i * 19 + j] > 0.f ? e : NEG_INF_F;
    v[j] = e;
    mx = fmaxf(mx, e);
  }
  float sum = 0.f;
#pragma unroll
  for (int j = 0; j < 19; ++j) { v[j] = expf(v[j] - mx); sum += v[j]; }
  float inv = 1.f / sum;
#pragma unroll
  for (int j = 0; j < 19; ++j) att[(size_t)bk * 361 + i * 19 + j] = v[j] * inv;
}

// ---------------- batch_attention = mean over heads -------------------------
__global__ __launch_bounds__(384) void batt_k(
    const float* __restrict__ att, float* __restrict__ out) {
  int b = blockIdx.x, t = threadIdx.x;
  if (t >= 361) return;
  float s = 0.f;
  for (int k = 0; k < 8; ++k) s += att[(size_t)(b * 8 + k) * 361 + t];
  out[3104 + b * 361 + t] = s * 0.125f;
}

// ---------------- h = att@Wh, elu, transpose into x (b,19,512) --------------
__global__ __launch_bounds__(64) void hx_k(
    const float* __restrict__ att, const float* __restrict__ Wh,
    float* __restrict__ xb) {
  int bid = blockIdx.x;           // b*152 + k*19 + i
  int i = bid % 19;
  int k = (bid / 19) % 8;
  int b = bid / 152;
  int h = threadIdx.x;
  const float* ar = att + (size_t)(b * 8 + k) * 361 + i * 19;
  const float* whp = Wh + (size_t)((b * 8 + k) * 19) * 64 + h;
  float s = 0.f;
#pragma unroll
  for (int j = 0; j < 19; ++j) s = fmaf(ar[j], whp[j * 64], s);
  float e = s > 0.f ? s : expm1f(s);
  xb[((size_t)b * 19 + i) * 512 + k * 64 + h] = e;
}

// ---------------- Wh2 = x @ out_W, plus o1/o2 projections -------------------
__global__ __launch_bounds__(128) void wh2_k(
    const float* __restrict__ xb, const float* __restrict__ outW,
    const float* __restrict__ oa, float* __restrict__ Wh2,
    float* __restrict__ o1, float* __restrict__ o2) {
  int bn = blockIdx.x, t = threadIdx.x;  // bn = b*19+n
  __shared__ float sx[512];
  __shared__ float r1[128], r2[128];
  for (int m = t; m < 512; m += 128) sx[m] = xb[(size_t)bn * 512 + m];
  __syncthreads();
  float a = 0.f;
  for (int m = 0; m < 512; ++m) a = fmaf(sx[m], outW[m * 128 + t], a);
  Wh2[(size_t)bn * 128 + t] = a;
  r1[t] = a * oa[t];
  r2[t] = a * oa[128 + t];
  __syncthreads();
  for (int s = 64; s > 0; s >>= 1) {
    if (t < s) { r1[t] += r1[t + s]; r2[t] += r2[t + s]; }
    __syncthreads();
  }
  if (t == 0) { o1[bn] = r1[0]; o2[bn] = r2[0]; }
}

// ---------------- layer-2 attention row 0 + heads ---------------------------
__global__ __launch_bounds__(256) void final_k(
    const float* __restrict__ adj, const float* __restrict__ o1,
    const float* __restrict__ o2, const float* __restrict__ Wh2,
    const float* __restrict__ llw, const float* __restrict__ llb,
    const float* __restrict__ fcw, const float* __restrict__ fcb,
    float* __restrict__ out) {
  int b = blockIdx.x, t = threadIdx.x;
  __shared__ float sA[19], sF[128], sG[256];
  if (t < 19) {
    float e = o1[b * 19] + o2[b * 19 + t];
    e = e >= 0.f ? e : 0.2f * e;
    sA[t] = adj[t] > 0.f ? e : NEG_INF_F;  // adj row 0
  }
  __syncthreads();
  if (t == 0) {
    float mx = -1e30f;
    for (int j = 0; j < 19; ++j) mx = fmaxf(mx, sA[j]);
    float sum = 0.f;
    for (int j = 0; j < 19; ++j) { sA[j] = expf(sA[j] - mx); sum += sA[j]; }
    float inv = 1.f / sum;
    for (int j = 0; j < 19; ++j) sA[j] *= inv;
  }
  __syncthreads();
  if (t < 128) {
    float s = 0.f;
    for (int j = 0; j < 19; ++j) s = fmaf(sA[j], Wh2[(size_t)(b * 19 + j) * 128 + t], s);
    sF[t] = s > 0.f ? s : expm1f(s);
  }
  __syncthreads();
  {
    float a = llb[t];
    for (int e = 0; e < 128; ++e) a = fmaf(sF[e], llw[e * 256 + t], a);
    a = fmaxf(a, 0.f);
    sG[t] = a;
    out[1024 + b * 256 + t] = a;
  }
  __syncthreads();
  if (t < 2) {
    float a = fcb[t];
    for (int o = 0; o < 256; ++o) a = fmaf(sG[o], fcw[o * 2 + t], a);
    out[3072 + b * 2 + t] = a;
  }
}

// ---------------------------------------------------------------------------
extern "C" void kernel_launch(void* const* d_in, const int* in_sizes, int n_in,
                              void* d_out, int out_size, void* d_ws, size_t ws_size,
                              hipStream_t stream) {
  const float* in_img   = (const float*)d_in[0];
  const float* w1       = (const float*)d_in[1];
  const float* b1       = (const float*)d_in[2];
  const float* w2       = (const float*)d_in[3];
  const float* b2       = (const float*)d_in[4];
  const float* w3       = (const float*)d_in[5];
  const float* b3       = (const float*)d_in[6];
  const float* w4       = (const float*)d_in[7];
  const float* b4       = (const float*)d_in[8];
  const float* fc_cnn_w = (const float*)d_in[9];
  const float* fc_cnn_b = (const float*)d_in[10];
  const float* att_W    = (const float*)d_in[11];
  const float* att_a    = (const float*)d_in[12];
  const float* out_W    = (const float*)d_in[13];
  const float* out_a    = (const float*)d_in[14];
  const float* ll_w     = (const float*)d_in[15];
  const float* ll_b     = (const float*)d_in[16];
  const float* fc_w     = (const float*)d_in[17];
  const float* fc_b     = (const float*)d_in[18];
  const float* sfc_w    = (const float*)d_in[19];
  const float* sfc_b    = (const float*)d_in[20];
  float* out = (float*)d_out;

  float* p = (float*)d_ws;
  float* adj   = p; p += 361;
  float* feats = p; p += 16384;      // 128 x 128
  float* Wh    = p; p += 77824;      // 8*8*19*64
  float* f1    = p; p += 1216;
  float* f2    = p; p += 1216;
  float* att   = p; p += 23104;      // 8*8*361
  float* xb    = p; p += 77824;      // 8*19*512
  float* Wh2   = p; p += 19456;      // 8*19*128
  float* o1    = p; p += 152;
  float* o2    = p; p += 152;
  size_t small_floats = (size_t)(p - (float*)d_ws);

  // choose largest image-chunk (divisor of 128) whose ping-pong buffers fit ws
  int chunk = 128;
  while (chunk > 1 &&
         (small_floats + (size_t)chunk * (131072 + 65536)) * sizeof(float) > ws_size)
    chunk >>= 1;
  float* bufA = p; p += (size_t)chunk * 131072;  // max(conv1 out, conv3 out)
  float* bufB = p;                               // max(conv2 out, conv4 out)

  adj_build_k<<<1, 384, 0, stream>>>(adj);

  for (int c0 = 0; c0 < 128; c0 += chunk) {
    conv1_pool_k<<<dim3(16, 32, chunk), 256, 0, stream>>>(
        in_img + (size_t)c0 * 16384, w1, b1, bufA);
    conv_pool_k<32, 64, 64><<<dim3(16, 4, chunk), 256, 0, stream>>>(bufA, w2, b2, bufB);
    conv_pool_k<64, 128, 32><<<dim3(4, 8, chunk), 256, 0, stream>>>(bufB, w3, b3, bufA);
    conv_pool_k<128, 128, 16><<<dim3(1, 8, chunk), 256, 0, stream>>>(bufA, w4, b4, bufB);
    meanfc_k<<<chunk, 128, 0, stream>>>(bufB, fc_cnn_w, fc_cnn_b, feats, c0);
  }

  sh_k<<<8, 128, 0, stream>>>(feats, sfc_w, sfc_b, out);
  wh_k<<<1216, 64, 0, stream>>>(feats, att_W, att_a, Wh, f1, f2);
  att_k<<<64, 64, 0, stream>>>(f1, f2, adj, att);
  batt_k<<<8, 384, 0, stream>>>(att, out);
  hx_k<<<1216, 64, 0, stream>>>(att, Wh, xb);
  wh2_k<<<152, 128, 0, stream>>>(xb, out_W, out_a, Wh2, o1, o2);
  final_k<<<8, 256, 0, stream>>>(adj, o1, o2, Wh2, ll_w, ll_b, fc_w, fc_b, out);
}